// Round 6
// baseline (94.579 us; speedup 1.0000x reference)
//
#include <hip/hip_runtime.h>
#include <math.h>

#define DIM 9
#define SINE_AMP 0.1f
#define NOISE_STD 0.003f

typedef float f32x4 __attribute__((ext_vector_type(4)));
typedef float f32x2 __attribute__((ext_vector_type(2)));

// ===========================================================================
// FUSED kernel (upp == 512 fast path).
// One block = 1024 contiguous elements of one batch => spans <= 2 frames
// (1024 < upp*DIM = 4608). Prologue: per-block double SUM of rad over
// l' < l0 (exact f32 rad semantics incl. +rand_ini at l=0), wave-reduce,
// build 2x9 {rad, base} LDS table (zeroed for unvoiced frames so sin()=0
// replaces the uv multiply). Main loop: pure streaming, plain ld/st
// (nontemporal hints hurt on gfx950: 53.8 -> 57.3 us measured).
// ===========================================================================
__global__ void __launch_bounds__(256)
fused_sine_kernel(const float* __restrict__ f0,
                  const float* __restrict__ rand_ini,
                  const float* __restrict__ noise_randn,
                  float* __restrict__ out_sine,
                  float* __restrict__ out_uv,
                  float* __restrict__ out_noise,
                  int L, int Lo)
{
    const int b    = blockIdx.y;
    const int tid  = threadIdx.x;
    const int lane = tid & 63, wid = tid >> 6;
    const int LoD  = Lo * DIM;
    const unsigned n4 = (unsigned)LoD >> 2;

    const float* __restrict__ f0_b = f0 + b * L;

    const unsigned e0 = (unsigned)blockIdx.x * 1024u;   // first element of block
    const int l0 = (int)(e0 / (512u * 9u));             // first frame touched

    // ---- prologue: S_d = sum_{l' < l0} rad_f32[l',d] in double ----
    double acc[DIM];
    #pragma unroll
    for (int d = 0; d < DIM; ++d) acc[d] = 0.0;

    for (int l = tid; l < l0; l += 256) {
        const float fv = f0_b[l];
        #pragma unroll
        for (int d = 0; d < DIM; ++d) {
            // reference: rad = (f0 * h / SR) % 1.0, all f32, then += ri at l==0
            float r = fmodf(fv * (float)(d + 1) / 48000.0f, 1.0f);
            if (l == 0) r += (d == 0) ? 0.0f : rand_ini[b * DIM + d];
            acc[d] += (double)r;
        }
    }
    #pragma unroll
    for (int d = 0; d < DIM; ++d) {
        double v = acc[d];
        #pragma unroll
        for (int off = 32; off > 0; off >>= 1)
            v += __shfl_down(v, off, 64);
        acc[d] = v;
    }
    __shared__ double wsum[4][DIM];
    __shared__ f32x2  tab[2][DIM];     // {rad, base} for rows l0, l0+1
    if (lane == 0) {
        #pragma unroll
        for (int d = 0; d < DIM; ++d) wsum[wid][d] = acc[d];
    }
    __syncthreads();
    if (tid < DIM) {
        const int d = tid;
        double S = wsum[0][d] + wsum[1][d] + wsum[2][d] + wsum[3][d];
        #pragma unroll
        for (int row = 0; row < 2; ++row) {
            const int l = l0 + row;
            f32x2 e; e.x = 0.0f; e.y = 0.0f;
            if (l < L) {
                const float fv = f0_b[l];
                float r = fmodf(fv * (float)(d + 1) / 48000.0f, 1.0f);
                if (l == 0) r += (d == 0) ? 0.0f : rand_ini[b * DIM + d];
                double bf = S * 512.0;            // upp * prefix
                bf -= floor(bf);                  // frac in double
                if (fv > 0.0f) { e.x = r; e.y = (float)bf; }  // uv-fold
                S += (double)r;                   // includes ri at l==0
            }
            tab[row][d] = e;
        }
    }
    __syncthreads();

    // ---- main streaming loop: exactly one float4 triple per thread ----
    const long long boff = (long long)b * LoD;
    const f32x4* __restrict__ nz_b    = (const f32x4*)(noise_randn + boff);
    f32x4* __restrict__       sine_b  = (f32x4*)(out_sine + boff);
    f32x4* __restrict__       noise_b = (f32x4*)(out_noise + boff);

    const unsigned i4 = (e0 >> 2) + (unsigned)tid;
    if (i4 < n4) {
        const f32x4 nr = nz_b[i4];
        const unsigned rem0 = i4 << 2;
        unsigned o = rem0 / 9u;                 // one magic-div per thread
        unsigned d = rem0 - o * 9u;
        f32x4 sv, nv;
        #pragma unroll
        for (int k = 0; k < 4; ++k) {
            const unsigned j  = o & 511u;
            const int     row = (int)(o >> 9) - l0;   // 0 or 1
            const f32x2 rbv = tab[row][d];
            float ph = fmaf((float)(j + 1u), rbv.x, rbv.y);
            ph -= floorf(ph);                   // revolutions in [0,1)
            float s;
            asm("v_sin_f32 %0, %1" : "=v"(s) : "v"(ph));   // sin(2*pi*x)
            const float namp = (rbv.x > 0.0f) ? NOISE_STD : (SINE_AMP / 3.0f);
            const float nzv  = namp * nr[k];
            nv[k] = nzv;
            sv[k] = fmaf(s, SINE_AMP, nzv);
            if (k < 3) { ++d; if (d == 9u) { d = 0u; ++o; } }
        }
        sine_b[i4]  = sv;
        noise_b[i4] = nv;
    }

    // ---- uv output: first 500 blocks per batch, coalesced float4 ----
    const unsigned nu4 = (unsigned)Lo >> 2;
    const unsigned u4  = (unsigned)blockIdx.x * 256u + (unsigned)tid;
    if (u4 < nu4) {
        f32x4* __restrict__ uv_b4 = (f32x4*)(out_uv + (long long)b * Lo);
        const unsigned o0 = u4 << 2;
        f32x4 uvv;
        #pragma unroll
        for (int k = 0; k < 4; ++k) {
            const unsigned l = (o0 + (unsigned)k) >> 9;
            uvv[k] = (f0_b[l] > 0.0f) ? 1.0f : 0.0f;
        }
        uv_b4[u4] = uvv;
    }
}

// ===========================================================================
// Generic fallback (upp != 512): two-kernel path from round 5.
// ===========================================================================
__global__ void __launch_bounds__(1024)
phase_scan_kernel(const float* __restrict__ f0,
                  const float* __restrict__ rand_ini,
                  f32x2* __restrict__ rb_out,        // (B,L,DIM) {rad, base}
                  int B, int L, int upp)
{
    const int bd   = blockIdx.x;
    const int b    = bd / DIM;
    const int d    = bd - b * DIM;
    const int tid  = threadIdx.x;
    const int lane = tid & 63;
    const int wid  = tid >> 6;
    const float hf = (float)(d + 1);
    const float ri = (d == 0) ? 0.0f : rand_ini[b * DIM + d];

    __shared__ double partials[16];
    __shared__ double wave_off[17];

    double carry = 0.0;
    for (int c0 = 0; c0 < L; c0 += 1024) {
        const int l = c0 + tid;
        float r = 0.0f, fv = 0.0f;
        if (l < L) {
            fv = f0[b * L + l];
            r = fmodf(fv * hf / 48000.0f, 1.0f);
            if (l == 0) r += ri;
        }
        const double rd = (double)r;
        double inc = rd;
        #pragma unroll
        for (int off = 1; off < 64; off <<= 1) {
            double t = __shfl_up(inc, off, 64);
            if (lane >= off) inc += t;
        }
        if (lane == 63) partials[wid] = inc;
        __syncthreads();
        if (tid == 0) {
            double run = 0.0;
            #pragma unroll
            for (int w = 0; w < 16; ++w) { wave_off[w] = run; run += partials[w]; }
            wave_off[16] = run;
        }
        __syncthreads();
        if (l < L) {
            const double excl = carry + wave_off[wid] + (inc - rd);
            double bf = excl * (double)upp;
            bf -= floor(bf);
            const bool voiced = fv > 0.0f;
            f32x2 rbv;
            rbv.x = voiced ? r : 0.0f;
            rbv.y = voiced ? (float)bf : 0.0f;
            rb_out[(b * L + l) * DIM + d] = rbv;
        }
        carry += wave_off[16];
        __syncthreads();
    }
}

__global__ void __launch_bounds__(256)
sine_gen_kernel(const float* __restrict__ f0,
                const float* __restrict__ noise_randn,
                const f32x2* __restrict__ rb,
                float* __restrict__ out_sine,
                float* __restrict__ out_uv,
                float* __restrict__ out_noise,
                int L, int Lo, int upp)
{
    const unsigned uppv = (unsigned)upp;
    const int b   = blockIdx.y;
    const int LoD = Lo * DIM;
    const unsigned n4 = (unsigned)LoD >> 2;
    const long long boff = (long long)b * LoD;

    const f32x4* __restrict__ nz_b    = (const f32x4*)(noise_randn + boff);
    f32x4* __restrict__       sine_b  = (f32x4*)(out_sine + boff);
    f32x4* __restrict__       noise_b = (f32x4*)(out_noise + boff);
    const float*  __restrict__ f0_b   = f0 + b * L;
    const f32x2* __restrict__  rb_b   = rb + b * L * DIM;

    const unsigned tid    = blockIdx.x * blockDim.x + threadIdx.x;
    const unsigned stride = gridDim.x * blockDim.x;

    for (unsigned i4 = tid; i4 < n4; i4 += stride) {
        const unsigned i0 = i4 << 2;
        const f32x4 nr = nz_b[i4];
        unsigned o = i0 / 9u;
        unsigned d = i0 - o * 9u;
        f32x4 sv, nv;
        #pragma unroll
        for (int k = 0; k < 4; ++k) {
            const unsigned l = o / uppv;
            const unsigned j = o - l * uppv;
            const f32x2 rbv = rb_b[l * 9u + d];
            float ph = fmaf((float)(j + 1u), rbv.x, rbv.y);
            ph -= floorf(ph);
            float s;
            asm("v_sin_f32 %0, %1" : "=v"(s) : "v"(ph));
            const float namp = (rbv.x > 0.0f) ? NOISE_STD : (SINE_AMP / 3.0f);
            const float nzv = namp * nr[k];
            nv[k] = nzv;
            sv[k] = fmaf(s, SINE_AMP, nzv);
            if (k < 3) { ++d; if (d == 9u) { d = 0u; ++o; } }
        }
        sine_b[i4]  = sv;
        noise_b[i4] = nv;
    }

    f32x4* __restrict__ uv_b4 = (f32x4*)(out_uv + (long long)b * Lo);
    const unsigned nu4 = (unsigned)Lo >> 2;
    for (unsigned u4 = tid; u4 < nu4; u4 += stride) {
        const unsigned o0 = u4 << 2;
        f32x4 uvv;
        #pragma unroll
        for (int k = 0; k < 4; ++k) {
            const unsigned l = (o0 + (unsigned)k) / uppv;
            uvv[k] = (f0_b[l] > 0.0f) ? 1.0f : 0.0f;
        }
        uv_b4[u4] = uvv;
    }

    if (blockIdx.x == 0 && threadIdx.x < (unsigned)(LoD & 3)) {
        const unsigned rem = (n4 << 2) + threadIdx.x;
        const unsigned o = rem / 9u;
        const unsigned d = rem - o * 9u;
        const unsigned l = o / uppv;
        const unsigned j = o - l * uppv;
        const f32x2 rbv = rb_b[l * 9u + d];
        float ph = fmaf((float)(j + 1u), rbv.x, rbv.y);
        ph -= floorf(ph);
        float s;
        asm("v_sin_f32 %0, %1" : "=v"(s) : "v"(ph));
        const float namp = (rbv.x > 0.0f) ? NOISE_STD : (SINE_AMP / 3.0f);
        const float nzv = namp * ((const float*)nz_b)[rem];
        ((float*)noise_b)[rem] = nzv;
        ((float*)sine_b)[rem]  = fmaf(s, SINE_AMP, nzv);
    }
    if (blockIdx.x == 0 && threadIdx.x < (unsigned)(Lo & 3)) {
        const unsigned o = (nu4 << 2) + threadIdx.x;
        const unsigned l = o / uppv;
        ((float*)uv_b4)[o] = (f0_b[l] > 0.0f) ? 1.0f : 0.0f;
    }
}

extern "C" void kernel_launch(void* const* d_in, const int* in_sizes, int n_in,
                              void* d_out, int out_size, void* d_ws, size_t ws_size,
                              hipStream_t stream)
{
    const float* f0       = (const float*)d_in[0];
    const float* rand_ini = (const float*)d_in[1];
    const float* noise    = (const float*)d_in[2];
    const int B  = in_sizes[1] / DIM;        // rand_ini is (B, DIM)
    const int L  = in_sizes[0] / B;          // f0 is (B, L)
    const int Lo = in_sizes[2] / (B * DIM);  // noise_randn is (B, Lo, DIM)
    const int upp = Lo / L;

    float* out       = (float*)d_out;
    float* out_sine  = out;
    float* out_uv    = out_sine + (long long)B * Lo * DIM;
    float* out_noise = out_uv + (long long)B * Lo;

    if (upp == 512 && (Lo & 3) == 0) {
        const int LoD = Lo * DIM;
        const int bx  = (LoD + 1023) / 1024;
        fused_sine_kernel<<<dim3(bx, B), dim3(256), 0, stream>>>(
            f0, rand_ini, noise, out_sine, out_uv, out_noise, L, Lo);
    } else {
        f32x2* rb_ws = (f32x2*)d_ws;
        phase_scan_kernel<<<dim3(B * DIM), dim3(1024), 0, stream>>>(
            f0, rand_ini, rb_ws, B, L, upp);
        const int n4 = (Lo * DIM) >> 2;
        int bx = (n4 + 255) / 256;
        if (bx > 1024) bx = 1024;
        dim3 grid(bx, B);
        sine_gen_kernel<<<grid, dim3(256), 0, stream>>>(
            f0, noise, rb_ws, out_sine, out_uv, out_noise, L, Lo, upp);
    }
}

// Round 7
// 46.568 us; speedup vs baseline: 2.0310x; 2.0310x over previous
//
#include <hip/hip_runtime.h>
#include <math.h>

#define DIM 9
#define SINE_AMP 0.1f
#define NOISE_STD 0.003f

typedef float f32x4 __attribute__((ext_vector_type(4)));
typedef float f32x2 __attribute__((ext_vector_type(2)));

// ---------------------------------------------------------------------------
// Kernel 1: one 1024-thread block per (b, d) chain — single-pass block scan
// (L=1000 fits one chunk). rad with exact f32 reference semantics;
// base = frac(upp * prefix_sum(rad)) via double scan. uv folded: unvoiced
// frames store rad=base=0 (sin(0)=0 == sine*uv; voiced rad always > 0).
// ---------------------------------------------------------------------------
__global__ void __launch_bounds__(1024)
phase_scan_kernel(const float* __restrict__ f0,
                  const float* __restrict__ rand_ini,
                  f32x2* __restrict__ rb_out,        // (B,L,DIM) {rad, base}
                  int B, int L, int upp)
{
    const int bd   = blockIdx.x;
    const int b    = bd / DIM;
    const int d    = bd - b * DIM;
    const int tid  = threadIdx.x;
    const int lane = tid & 63;
    const int wid  = tid >> 6;
    const float hf = (float)(d + 1);
    const float ri = (d == 0) ? 0.0f : rand_ini[b * DIM + d];

    __shared__ double partials[16];
    __shared__ double wave_off[17];

    double carry = 0.0;
    for (int c0 = 0; c0 < L; c0 += 1024) {
        const int l = c0 + tid;
        float r = 0.0f, fv = 0.0f;
        if (l < L) {
            fv = f0[b * L + l];
            r = fmodf(fv * hf / 48000.0f, 1.0f);
            if (l == 0) r += ri;
        }
        const double rd = (double)r;
        double inc = rd;
        #pragma unroll
        for (int off = 1; off < 64; off <<= 1) {
            double t = __shfl_up(inc, off, 64);
            if (lane >= off) inc += t;
        }
        if (lane == 63) partials[wid] = inc;
        __syncthreads();
        if (tid == 0) {
            double run = 0.0;
            #pragma unroll
            for (int w = 0; w < 16; ++w) { wave_off[w] = run; run += partials[w]; }
            wave_off[16] = run;
        }
        __syncthreads();
        if (l < L) {
            const double excl = carry + wave_off[wid] + (inc - rd);
            double bf = excl * (double)upp;
            bf -= floor(bf);
            const bool voiced = fv > 0.0f;
            f32x2 rbv;
            rbv.x = voiced ? r : 0.0f;
            rbv.y = voiced ? (float)bf : 0.0f;
            rb_out[(b * L + l) * DIM + d] = rbv;
        }
        carry += wave_off[16];
        __syncthreads();
    }
}

// ---------------------------------------------------------------------------
// Kernel 2 (upp==512 fast path): exact-fit, 2 float4-triples per thread.
// Block = 2048 contiguous elements => spans <= 2 frames (2048 < 512*9=4608).
// Prologue: 18 threads stage the 2x9 {rad,base} table global->LDS.
// Main: both nz loads issued first (MLP=2), table reads from LDS, plain
// stores (nontemporal hints hurt on gfx950: 53.8 -> 57.3 us measured).
// ---------------------------------------------------------------------------
__global__ void __launch_bounds__(256)
sine_gen512_kernel(const float* __restrict__ f0,
                   const float* __restrict__ noise_randn,
                   const f32x2* __restrict__ rb,
                   float* __restrict__ out_sine,
                   float* __restrict__ out_uv,
                   float* __restrict__ out_noise,
                   int L, int Lo)
{
    const int b   = blockIdx.y;
    const int tid = threadIdx.x;
    const int LoD = Lo * DIM;
    const unsigned n4  = (unsigned)LoD >> 2;
    const unsigned nu4 = (unsigned)Lo >> 2;

    const long long boff = (long long)b * LoD;
    const f32x4* __restrict__ nz_b    = (const f32x4*)(noise_randn + boff);
    f32x4* __restrict__       sine_b  = (f32x4*)(out_sine + boff);
    f32x4* __restrict__       noise_b = (f32x4*)(out_noise + boff);
    const float* __restrict__ f0_b    = f0 + b * L;
    const f32x2* __restrict__ rb_b    = rb + b * L * DIM;

    // ---- stage 2x9 {rad, base} table into LDS ----
    const unsigned e0 = (unsigned)blockIdx.x * 2048u;   // block's first element
    const int l0 = (int)(e0 / 4608u);                   // first frame touched
    __shared__ f32x2 tab[2][DIM];
    if (tid < 2 * DIM) {
        const int row = tid / DIM, d = tid - row * DIM;
        const int l = l0 + row;
        f32x2 e; e.x = 0.0f; e.y = 0.0f;
        if (l < L) e = rb_b[l * DIM + d];
        tab[row][d] = e;
    }
    __syncthreads();

    // ---- main: thread owns elements [p*8, p*8+8) ----
    const unsigned p   = (unsigned)blockIdx.x * 256u + (unsigned)tid;
    const unsigned i4a = p << 1, i4b = i4a + 1u;
    if (i4a < n4) {
        const bool hasb = (i4b < n4);
        const f32x4 nra = nz_b[i4a];                    // both loads first
        f32x4 nrb;
        if (hasb) nrb = nz_b[i4b];

        const unsigned rem0 = i4a << 2;                 // = p*8
        unsigned o = rem0 / 9u;                         // one magic-div
        unsigned d = rem0 - o * 9u;
        f32x4 sv0, nv0, sv1, nv1;
        #pragma unroll
        for (int k = 0; k < 8; ++k) {
            const unsigned j  = o & 511u;
            const int    row  = (int)(o >> 9) - l0;     // 0 or 1
            const f32x2 rbv = tab[row][d];
            float ph = fmaf((float)(j + 1u), rbv.x, rbv.y);
            ph -= floorf(ph);                           // revolutions [0,1)
            float s;
            asm("v_sin_f32 %0, %1" : "=v"(s) : "v"(ph));     // sin(2*pi*x)
            const float namp = (rbv.x > 0.0f) ? NOISE_STD : (SINE_AMP / 3.0f);
            const float nz   = namp * ((k < 4) ? nra[k & 3] : nrb[k & 3]);
            const float sn   = fmaf(s, SINE_AMP, nz);
            if (k < 4) { nv0[k & 3] = nz; sv0[k & 3] = sn; }
            else       { nv1[k & 3] = nz; sv1[k & 3] = sn; }
            if (k < 7) { ++d; if (d == 9u) { d = 0u; ++o; } }
        }
        sine_b[i4a]  = sv0;
        noise_b[i4a] = nv0;
        if (hasb) { sine_b[i4b] = sv1; noise_b[i4b] = nv1; }
    }

    // ---- uv output: first nu4 threads per batch, coalesced float4 ----
    if (p < nu4) {
        f32x4* __restrict__ uv_b4 = (f32x4*)(out_uv + (long long)b * Lo);
        const unsigned o0 = p << 2;
        f32x4 uvv;
        #pragma unroll
        for (int k = 0; k < 4; ++k) {
            const unsigned l = (o0 + (unsigned)k) >> 9;
            uvv[k] = (f0_b[l] > 0.0f) ? 1.0f : 0.0f;
        }
        uv_b4[p] = uvv;
    }
}

// ---------------------------------------------------------------------------
// Generic fallback kernel 2 (upp != 512): round-5 version.
// ---------------------------------------------------------------------------
__global__ void __launch_bounds__(256)
sine_gen_kernel(const float* __restrict__ f0,
                const float* __restrict__ noise_randn,
                const f32x2* __restrict__ rb,
                float* __restrict__ out_sine,
                float* __restrict__ out_uv,
                float* __restrict__ out_noise,
                int L, int Lo, int upp)
{
    const unsigned uppv = (unsigned)upp;
    const int b   = blockIdx.y;
    const int LoD = Lo * DIM;
    const unsigned n4 = (unsigned)LoD >> 2;
    const long long boff = (long long)b * LoD;

    const f32x4* __restrict__ nz_b    = (const f32x4*)(noise_randn + boff);
    f32x4* __restrict__       sine_b  = (f32x4*)(out_sine + boff);
    f32x4* __restrict__       noise_b = (f32x4*)(out_noise + boff);
    const float*  __restrict__ f0_b   = f0 + b * L;
    const f32x2* __restrict__  rb_b   = rb + b * L * DIM;

    const unsigned tid    = blockIdx.x * blockDim.x + threadIdx.x;
    const unsigned stride = gridDim.x * blockDim.x;

    for (unsigned i4 = tid; i4 < n4; i4 += stride) {
        const unsigned i0 = i4 << 2;
        const f32x4 nr = nz_b[i4];
        unsigned o = i0 / 9u;
        unsigned d = i0 - o * 9u;
        f32x4 sv, nv;
        #pragma unroll
        for (int k = 0; k < 4; ++k) {
            const unsigned l = o / uppv;
            const unsigned j = o - l * uppv;
            const f32x2 rbv = rb_b[l * 9u + d];
            float ph = fmaf((float)(j + 1u), rbv.x, rbv.y);
            ph -= floorf(ph);
            float s;
            asm("v_sin_f32 %0, %1" : "=v"(s) : "v"(ph));
            const float namp = (rbv.x > 0.0f) ? NOISE_STD : (SINE_AMP / 3.0f);
            const float nzv = namp * nr[k];
            nv[k] = nzv;
            sv[k] = fmaf(s, SINE_AMP, nzv);
            if (k < 3) { ++d; if (d == 9u) { d = 0u; ++o; } }
        }
        sine_b[i4]  = sv;
        noise_b[i4] = nv;
    }

    f32x4* __restrict__ uv_b4 = (f32x4*)(out_uv + (long long)b * Lo);
    const unsigned nu4 = (unsigned)Lo >> 2;
    for (unsigned u4 = tid; u4 < nu4; u4 += stride) {
        const unsigned o0 = u4 << 2;
        f32x4 uvv;
        #pragma unroll
        for (int k = 0; k < 4; ++k) {
            const unsigned l = (o0 + (unsigned)k) / uppv;
            uvv[k] = (f0_b[l] > 0.0f) ? 1.0f : 0.0f;
        }
        uv_b4[u4] = uvv;
    }

    if (blockIdx.x == 0 && threadIdx.x < (unsigned)(LoD & 3)) {
        const unsigned rem = (n4 << 2) + threadIdx.x;
        const unsigned o = rem / 9u;
        const unsigned d = rem - o * 9u;
        const unsigned l = o / uppv;
        const unsigned j = o - l * uppv;
        const f32x2 rbv = rb_b[l * 9u + d];
        float ph = fmaf((float)(j + 1u), rbv.x, rbv.y);
        ph -= floorf(ph);
        float s;
        asm("v_sin_f32 %0, %1" : "=v"(s) : "v"(ph));
        const float namp = (rbv.x > 0.0f) ? NOISE_STD : (SINE_AMP / 3.0f);
        const float nzv = namp * ((const float*)nz_b)[rem];
        ((float*)noise_b)[rem] = nzv;
        ((float*)sine_b)[rem]  = fmaf(s, SINE_AMP, nzv);
    }
    if (blockIdx.x == 0 && threadIdx.x < (unsigned)(Lo & 3)) {
        const unsigned o = (nu4 << 2) + threadIdx.x;
        const unsigned l = o / uppv;
        ((float*)uv_b4)[o] = (f0_b[l] > 0.0f) ? 1.0f : 0.0f;
    }
}

extern "C" void kernel_launch(void* const* d_in, const int* in_sizes, int n_in,
                              void* d_out, int out_size, void* d_ws, size_t ws_size,
                              hipStream_t stream)
{
    const float* f0       = (const float*)d_in[0];
    const float* rand_ini = (const float*)d_in[1];
    const float* noise    = (const float*)d_in[2];
    const int B  = in_sizes[1] / DIM;        // rand_ini is (B, DIM)
    const int L  = in_sizes[0] / B;          // f0 is (B, L)
    const int Lo = in_sizes[2] / (B * DIM);  // noise_randn is (B, Lo, DIM)
    const int upp = Lo / L;

    float* out       = (float*)d_out;
    float* out_sine  = out;
    float* out_uv    = out_sine + (long long)B * Lo * DIM;
    float* out_noise = out_uv + (long long)B * Lo;

    f32x2* rb_ws = (f32x2*)d_ws;

    phase_scan_kernel<<<dim3(B * DIM), dim3(1024), 0, stream>>>(
        f0, rand_ini, rb_ws, B, L, upp);

    if (upp == 512) {
        const int LoD = Lo * DIM;                 // Lo*9, divisible by 8
        const int bx  = (LoD + 2047) / 2048;      // 2048 elements per block
        sine_gen512_kernel<<<dim3(bx, B), dim3(256), 0, stream>>>(
            f0, noise, rb_ws, out_sine, out_uv, out_noise, L, Lo);
    } else {
        const int n4 = (Lo * DIM) >> 2;
        int bx = (n4 + 255) / 256;
        if (bx > 1024) bx = 1024;
        dim3 grid(bx, B);
        sine_gen_kernel<<<grid, dim3(256), 0, stream>>>(
            f0, noise, rb_ws, out_sine, out_uv, out_noise, L, Lo, upp);
    }
}

// Round 8
// 44.423 us; speedup vs baseline: 2.1290x; 1.0483x over previous
//
#include <hip/hip_runtime.h>
#include <math.h>

#define DIM 9
#define SINE_AMP 0.1f
#define NOISE_STD 0.003f

typedef float f32x4 __attribute__((ext_vector_type(4)));
typedef float f32x2 __attribute__((ext_vector_type(2)));

// ---------------------------------------------------------------------------
// Kernel 1: one 1024-thread block per (b, d) chain — single-pass block scan.
// rad[b,l,d] with exact f32 reference semantics;
// base[b,l,d] = frac( upp * sum_{l' < l} rad[b,l',d] ) via a double scan.
// uv folded in: unvoiced frames store rad=base=0 (sin(0)=0 == sine*uv), and
// voiced frames always have rad>0 (f0*h/48000 < 0.075, plus ri>=0 at l=0),
// so downstream voiced-ness is recovered as (rad > 0) — no namp table needed.
// ---------------------------------------------------------------------------
__global__ void __launch_bounds__(1024)
phase_scan_kernel(const float* __restrict__ f0,
                  const float* __restrict__ rand_ini,
                  f32x2* __restrict__ rb_out,        // (B,L,DIM) {rad, base}
                  int B, int L, int upp)
{
    const int bd   = blockIdx.x;        // b*DIM + d
    const int b    = bd / DIM;
    const int d    = bd - b * DIM;
    const int tid  = threadIdx.x;
    const int lane = tid & 63;
    const int wid  = tid >> 6;          // 0..15
    const float hf = (float)(d + 1);
    const float ri = (d == 0) ? 0.0f : rand_ini[b * DIM + d];

    __shared__ double partials[16];
    __shared__ double wave_off[17];     // [16] = chunk total

    double carry = 0.0;
    for (int c0 = 0; c0 < L; c0 += 1024) {
        const int l = c0 + tid;
        float r = 0.0f, fv = 0.0f;
        if (l < L) {
            fv = f0[b * L + l];
            // reference: f0_buf = f0 * h (f32); rad = (f0_buf / SR) % 1.0 (f32)
            r = fmodf(fv * hf / 48000.0f, 1.0f);
            if (l == 0) r += ri;        // rand_ini added at frame 0 (f32 add)
        }
        const double rd = (double)r;
        double inc = rd;
        // wave-64 inclusive scan in double
        #pragma unroll
        for (int off = 1; off < 64; off <<= 1) {
            double t = __shfl_up(inc, off, 64);
            if (lane >= off) inc += t;
        }
        if (lane == 63) partials[wid] = inc;
        __syncthreads();
        if (tid == 0) {
            double run = 0.0;
            #pragma unroll
            for (int w = 0; w < 16; ++w) { wave_off[w] = run; run += partials[w]; }
            wave_off[16] = run;
        }
        __syncthreads();
        if (l < L) {
            const double excl = carry + wave_off[wid] + (inc - rd);
            double bf = excl * (double)upp;
            bf -= floor(bf);                          // frac in double
            const bool voiced = fv > 0.0f;
            f32x2 rbv;
            rbv.x = voiced ? r : 0.0f;
            rbv.y = voiced ? (float)bf : 0.0f;
            rb_out[(b * L + l) * DIM + d] = rbv;
        }
        carry += wave_off[16];
        __syncthreads();   // partials reused next chunk
    }
}

// ---------------------------------------------------------------------------
// Kernel 2: fully parallel sample generation, pure streaming (PLAIN ld/st —
// nontemporal hints measurably hurt store BW on gfx950: 53.8 -> 57.3 us).
// Per float4: 1 magic-div for (o,d), incremental wrap after; namp derived
// from rad>0 (no table). 7 VMEM / iter. Best measured config: 44.6 us
// (= the practical mixed-stream ceiling; LDS-table/fusion/MLP=2 variants
// all measured neutral-to-worse).
//   sine = fma(sin(frac(base + (j+1)*rad)), 0.1, namp*nz)   (uv pre-folded)
//   noise = namp*nz
// ---------------------------------------------------------------------------
template <int UPP>
__global__ void __launch_bounds__(256)
sine_gen_kernel(const float* __restrict__ f0,
                const float* __restrict__ noise_randn,
                const f32x2* __restrict__ rb,
                float* __restrict__ out_sine,
                float* __restrict__ out_uv,
                float* __restrict__ out_noise,
                int L, int Lo, int upp)
{
    const unsigned UPPD = (UPP > 0) ? (unsigned)UPP : 1u;   // compile-time divisor
    const unsigned uppv = (UPP > 0) ? (unsigned)UPP : (unsigned)upp;

    const int b   = blockIdx.y;
    const int LoD = Lo * DIM;
    const unsigned n4 = (unsigned)LoD >> 2;
    const long long boff = (long long)b * LoD;

    const f32x4* __restrict__ nz_b    = (const f32x4*)(noise_randn + boff);
    f32x4* __restrict__       sine_b  = (f32x4*)(out_sine + boff);
    f32x4* __restrict__       noise_b = (f32x4*)(out_noise + boff);
    const float*  __restrict__ f0_b   = f0 + b * L;
    const f32x2* __restrict__  rb_b   = rb + b * L * DIM;

    const unsigned tid    = blockIdx.x * blockDim.x + threadIdx.x;
    const unsigned stride = gridDim.x * blockDim.x;

    for (unsigned i4 = tid; i4 < n4; i4 += stride) {
        const unsigned i0 = i4 << 2;
        const f32x4 nr = nz_b[i4];
        unsigned o = i0 / 9u;               // one magic-div per iteration
        unsigned d = i0 - o * 9u;
        f32x4 sv, nv;
        #pragma unroll
        for (int k = 0; k < 4; ++k) {
            unsigned l, j;
            if (UPP > 0) { l = o / UPPD; j = o - l * UPPD; }        // shifts
            else         { l = o / (unsigned)upp; j = o - l * (unsigned)upp; }
            const f32x2 rbv = rb_b[l * 9u + d];     // {rad, base}, L1/L2-hit
            float ph = fmaf((float)(j + 1u), rbv.x, rbv.y);
            ph -= floorf(ph);                        // revolutions in [0,1)
            float s;
            asm("v_sin_f32 %0, %1" : "=v"(s) : "v"(ph));  // sin(2*pi*x)
            const float namp = (rbv.x > 0.0f) ? NOISE_STD : (SINE_AMP / 3.0f);
            const float nzv = namp * nr[k];
            nv[k] = nzv;
            sv[k] = fmaf(s, SINE_AMP, nzv);
            if (k < 3) {                     // incremental (o,d) with wrap
                ++d;
                if (d == 9u) { d = 0u; ++o; }   // compare+select, no branch
            }
        }
        sine_b[i4]  = sv;
        noise_b[i4] = nv;
    }

    // uv output: (B, Lo), fully coalesced float4 stores
    f32x4* __restrict__ uv_b4 = (f32x4*)(out_uv + (long long)b * Lo);
    const unsigned nu4 = (unsigned)Lo >> 2;
    for (unsigned u4 = tid; u4 < nu4; u4 += stride) {
        const unsigned o0 = u4 << 2;
        f32x4 uvv;
        #pragma unroll
        for (int k = 0; k < 4; ++k) {
            const unsigned o = o0 + (unsigned)k;
            const unsigned l = o / uppv;
            uvv[k] = (f0_b[l] > 0.0f) ? 1.0f : 0.0f;
        }
        uv_b4[u4] = uvv;
    }

    // tails (not hit for upp=512; cheap insurance for odd shapes)
    if (blockIdx.x == 0 && threadIdx.x < (unsigned)(LoD & 3)) {
        const unsigned rem = (n4 << 2) + threadIdx.x;
        const unsigned o = rem / 9u;
        const unsigned d = rem - o * 9u;
        const unsigned l = o / uppv;
        const unsigned j = o - l * uppv;
        const f32x2 rbv = rb_b[l * 9u + d];
        float ph = fmaf((float)(j + 1u), rbv.x, rbv.y);
        ph -= floorf(ph);
        float s;
        asm("v_sin_f32 %0, %1" : "=v"(s) : "v"(ph));
        const float namp = (rbv.x > 0.0f) ? NOISE_STD : (SINE_AMP / 3.0f);
        const float nzv = namp * ((const float*)nz_b)[rem];
        ((float*)noise_b)[rem] = nzv;
        ((float*)sine_b)[rem]  = fmaf(s, SINE_AMP, nzv);
    }
    if (blockIdx.x == 0 && threadIdx.x < (unsigned)(Lo & 3)) {
        const unsigned o = (nu4 << 2) + threadIdx.x;
        const unsigned l = o / uppv;
        ((float*)uv_b4)[o] = (f0_b[l] > 0.0f) ? 1.0f : 0.0f;
    }
}

extern "C" void kernel_launch(void* const* d_in, const int* in_sizes, int n_in,
                              void* d_out, int out_size, void* d_ws, size_t ws_size,
                              hipStream_t stream)
{
    const float* f0       = (const float*)d_in[0];
    const float* rand_ini = (const float*)d_in[1];
    const float* noise    = (const float*)d_in[2];
    const int B  = in_sizes[1] / DIM;        // rand_ini is (B, DIM)
    const int L  = in_sizes[0] / B;          // f0 is (B, L)
    const int Lo = in_sizes[2] / (B * DIM);  // noise_randn is (B, Lo, DIM)
    const int upp = Lo / L;

    float* out       = (float*)d_out;
    float* out_sine  = out;
    float* out_uv    = out_sine + (long long)B * Lo * DIM;
    float* out_noise = out_uv + (long long)B * Lo;

    f32x2* rb_ws = (f32x2*)d_ws;

    phase_scan_kernel<<<dim3(B * DIM), dim3(1024), 0, stream>>>(
        f0, rand_ini, rb_ws, B, L, upp);

    const int n4 = (Lo * DIM) >> 2;
    int bx = (n4 + 255) / 256;
    if (bx > 1024) bx = 1024;
    dim3 grid(bx, B);
    if (upp == 512) {
        sine_gen_kernel<512><<<grid, dim3(256), 0, stream>>>(
            f0, noise, rb_ws, out_sine, out_uv, out_noise, L, Lo, upp);
    } else {
        sine_gen_kernel<0><<<grid, dim3(256), 0, stream>>>(
            f0, noise, rb_ws, out_sine, out_uv, out_noise, L, Lo, upp);
    }
}